// Round 17
// baseline (176.032 us; speedup 1.0000x reference)
//
#include <hip/hip_runtime.h>

typedef _Float16 f16;
typedef _Float16 f16x8 __attribute__((ext_vector_type(8)));
typedef _Float16 f16x4 __attribute__((ext_vector_type(4)));
typedef __fp16 h16x2 __attribute__((ext_vector_type(2)));
typedef float f32x4 __attribute__((ext_vector_type(4)));

constexpr int HDIM = 256, WDIM = 256, C_ = 192, NH_ = 6;
constexpr float SCALE = 0.17677669529663687f;            // 32^-0.5
constexpr float L2E = 1.4426950408889634f;               // log2(e)
constexpr float SCALE2 = SCALE * L2E;                    // folded into q-weights
constexpr int XP = 200;                                  // padded f16 row stride

#define SCHED_FENCE() __builtin_amdgcn_sched_barrier(0)

// workspace layout (bytes)
constexpr size_t OFF_WQ   = 0;         // packed qkv weights (q rows pre-scaled): 221184 B
constexpr size_t OFF_WP   = 221184;    // packed proj weights: 73728 B
constexpr size_t OFF_BIAS = 294912;    // packed bias f32 (pre-scaled by log2e), C-layout: 98304 B

__global__ __launch_bounds__(256) void prep_kernel(const float* __restrict__ qkv_w,
                                                   const float* __restrict__ proj_w,
                                                   const float* __restrict__ rpb,
                                                   f16* __restrict__ wqp, f16* __restrict__ wpp,
                                                   float* __restrict__ biasp) {
    int i = blockIdx.x * 256 + threadIdx.x;
    if (i < 13824) {                       // qkv frags: entry = ((w*3+c)*2+dt)*6+ks
        int lane = i & 63, rest = i >> 6;
        int ks = rest % 6; rest /= 6;
        int dt = rest & 1; rest >>= 1;
        int c = rest % 3, w = rest / 3;
        int l15 = lane & 15, lg = lane >> 4;
        int row = c * 192 + w * 32 + dt * 16 + l15;
        int col = ks * 32 + lg * 8;
        float sc = (c == 0) ? SCALE2 : 1.0f;   // fold softmax scale*log2e into q-weights
#pragma unroll
        for (int j = 0; j < 8; ++j) wqp[(size_t)i * 8 + j] = (f16)(qkv_w[row * 192 + col + j] * sc);
    } else if (i < 18432) {                // proj frags: entry = (w*2+nt)*6+ks
        int g = i - 13824;
        int lane = g & 63, rest = g >> 6;
        int ks = rest % 6; rest /= 6;
        int nt = rest & 1, w = rest >> 1;
        int l15 = lane & 15, lg = lane >> 4;
        int row = w * 32 + nt * 16 + l15;
        int col = ks * 32 + lg * 8;
#pragma unroll
        for (int j = 0; j < 8; ++j) wpp[(size_t)g * 8 + j] = (f16)proj_w[row * 192 + col + j];
    } else if (i < 24576) {                // bias frags f32 (*log2e): entry = (h*4+qt)*4+kt
        int g = i - 18432;
        int lane = g & 63;
        int kt = (g >> 6) & 3, qt = (g >> 8) & 3, h = g >> 10;
        int q = qt * 16 + (lane & 15);
#pragma unroll
        for (int j = 0; j < 4; ++j) {
            int k = kt * 16 + (lane >> 4) * 4 + j;
            int dy = (q >> 3) - (k >> 3) + 7;
            int dx = (q & 7) - (k & 7) + 7;
            biasp[(size_t)g * 4 + j] = rpb[(dy * 15 + dx) * NH_ + h] * L2E;
        }
    }
}

// One block = one window, 2 waves x 3 heads each. 2-pass QKV (q+k share xt
// reads), bias injected as the QK^T MFMA C-initializer, softmax in exp2 domain,
// fences pin loads per phase.
__global__ __launch_bounds__(128, 3) void fused_kernel(const float* __restrict__ x,
                                                       const f16* __restrict__ wqp,
                                                       const f16* __restrict__ wpp,
                                                       const float* __restrict__ pb,
                                                       const float* __restrict__ biasp,
                                                       float* __restrict__ out) {
    __shared__ f16 xlds[64 * XP];   // 25600 B; x tile, later att tile
    const int tid = threadIdx.x;
    const int v = tid >> 6;          // wave id (0,1); handles heads 3v..3v+2
    const int lane = tid & 63;
    const int l15 = lane & 15, lg = lane >> 4;
    const int win = blockIdx.x;
    const int b = win >> 10, wy = (win >> 5) & 31, wx = win & 31;

    // ---- stage x -> LDS, coalesced float4s, 3 fenced groups of 8 ----
#pragma unroll
    for (int grp = 0; grp < 3; ++grp) {
#pragma unroll
        for (int it8 = 0; it8 < 8; ++it8) {
            int u = tid + (grp * 8 + it8) * 128;
            int row = u / 48, c4 = u - row * 48;
            int gy = wy * 8 + (row >> 3), gx = wx * 8 + (row & 7);
            float4 vv = *((const float4*)(x + ((size_t)((b * HDIM + gy) * WDIM + gx)) * C_ + c4 * 4));
            h16x2 p0 = __builtin_amdgcn_cvt_pkrtz(vv.x, vv.y);
            h16x2 p1 = __builtin_amdgcn_cvt_pkrtz(vv.z, vv.w);
            f16x4 o4;
            o4[0] = (f16)p0[0]; o4[1] = (f16)p0[1]; o4[2] = (f16)p1[0]; o4[3] = (f16)p1[1];
            *((f16x4*)(xlds + row * XP + c4 * 4)) = o4;
        }
        SCHED_FENCE();
    }
    __syncthreads();

    f16x4 oreg[3][4][2];   // O^T of this wave's 3 heads, held until att barrier

#pragma unroll
    for (int hh = 0; hh < 3; ++hh) {
        const int head = v * 3 + hh;
        const f16x8* wqb   = (const f16x8*)wqp + (size_t)head * 36 * 64 + lane;
        const f32x4* bbase = (const f32x4*)biasp + (size_t)head * 16 * 64 + lane;
        SCHED_FENCE();   // don't hoist this head's loads into previous head

        // ---- pass 1: q,k (shared xt reads) ----
        f16x4 qf[2][4], kf[2][4];
        {
            f32x4 aq[2][4], ak[2][4];
#pragma unroll
            for (int ii = 0; ii < 4; ++ii)
#pragma unroll
                for (int jj = 0; jj < 2; ++jj) {
                    f32x4 z = {0.f, 0.f, 0.f, 0.f};
                    aq[jj][ii] = z; ak[jj][ii] = z;
                }
#pragma unroll
            for (int ks = 0; ks < 6; ++ks) {
                f16x8 Wq0 = wqb[(size_t)(     ks) * 64], Wq1 = wqb[(size_t)( 6 + ks) * 64];
                f16x8 Wk0 = wqb[(size_t)(12 + ks) * 64], Wk1 = wqb[(size_t)(18 + ks) * 64];
#pragma unroll
                for (int tt = 0; tt < 4; ++tt) {
                    f16x8 xt = *((const f16x8*)(xlds + (tt * 16 + l15) * XP + ks * 32 + lg * 8));
                    aq[0][tt] = __builtin_amdgcn_mfma_f32_16x16x32_f16(Wq0, xt, aq[0][tt], 0, 0, 0);
                    aq[1][tt] = __builtin_amdgcn_mfma_f32_16x16x32_f16(Wq1, xt, aq[1][tt], 0, 0, 0);
                    ak[0][tt] = __builtin_amdgcn_mfma_f32_16x16x32_f16(Wk0, xt, ak[0][tt], 0, 0, 0);
                    ak[1][tt] = __builtin_amdgcn_mfma_f32_16x16x32_f16(Wk1, xt, ak[1][tt], 0, 0, 0);
                }
            }
#pragma unroll
            for (int dt = 0; dt < 2; ++dt)
#pragma unroll
                for (int tt = 0; tt < 4; ++tt)
#pragma unroll
                    for (int ii = 0; ii < 4; ++ii) {
                        qf[dt][tt][ii] = (f16)(aq[dt][tt][ii]);   // scale pre-folded in weights
                        kf[dt][tt][ii] = (f16)(ak[dt][tt][ii]);
                    }
        }
        SCHED_FENCE();

        // ---- pass 2: v ----
        f16x4 vf[4][2];
        {
            f32x4 av[4][2];
#pragma unroll
            for (int ii = 0; ii < 4; ++ii)
#pragma unroll
                for (int jj = 0; jj < 2; ++jj) { f32x4 z = {0.f,0.f,0.f,0.f}; av[ii][jj] = z; }
#pragma unroll
            for (int ks = 0; ks < 6; ++ks) {
                f16x8 W0 = wqb[(size_t)(24 + ks) * 64], W1 = wqb[(size_t)(30 + ks) * 64];
#pragma unroll
                for (int tt = 0; tt < 4; ++tt) {
                    f16x8 xt = *((const f16x8*)(xlds + (tt * 16 + l15) * XP + ks * 32 + lg * 8));
                    av[tt][0] = __builtin_amdgcn_mfma_f32_16x16x32_f16(xt, W0, av[tt][0], 0, 0, 0);
                    av[tt][1] = __builtin_amdgcn_mfma_f32_16x16x32_f16(xt, W1, av[tt][1], 0, 0, 0);
                }
            }
#pragma unroll
            for (int tt = 0; tt < 4; ++tt)
#pragma unroll
                for (int dt = 0; dt < 2; ++dt)
#pragma unroll
                    for (int ii = 0; ii < 4; ++ii)
                        vf[tt][dt][ii] = (f16)(av[tt][dt][ii]);
        }
        SCHED_FENCE();

        // ---- attention (exp2 domain); bias as MFMA C-init; O^T -> oreg ----
#pragma unroll
        for (int qt = 0; qt < 4; ++qt) {
            f32x4 s[4];
#pragma unroll
            for (int kt = 0; kt < 4; ++kt) {
                f32x4 bb = bbase[(size_t)(qt * 4 + kt) * 64];
                s[kt] = __builtin_amdgcn_mfma_f32_16x16x16f16(kf[0][kt], qf[0][qt], bb, 0, 0, 0);
                s[kt] = __builtin_amdgcn_mfma_f32_16x16x16f16(kf[1][kt], qf[1][qt], s[kt], 0, 0, 0);
            }
            float m = s[0][0];
#pragma unroll
            for (int kt = 0; kt < 4; ++kt)
#pragma unroll
                for (int ii = 0; ii < 4; ++ii) m = fmaxf(m, s[kt][ii]);
            m = fmaxf(m, __shfl_xor(m, 16));
            m = fmaxf(m, __shfl_xor(m, 32));
            float sum = 0.f;
            f16x4 pa[4];
#pragma unroll
            for (int kt = 0; kt < 4; ++kt)
#pragma unroll
                for (int ii = 0; ii < 4; ++ii) {
                    float e;
                    asm("v_exp_f32 %0, %1" : "=v"(e) : "v"(s[kt][ii] - m));   // 2^x
                    sum += e;
                    pa[kt][ii] = (f16)e;
                }
            sum += __shfl_xor(sum, 16);
            sum += __shfl_xor(sum, 32);
            const float rq = __builtin_amdgcn_rcpf(sum);

#pragma unroll
            for (int dt = 0; dt < 2; ++dt) {
                f32x4 z = {0.f, 0.f, 0.f, 0.f};
                f32x4 o0 = __builtin_amdgcn_mfma_f32_16x16x16f16(vf[0][dt], pa[0], z, 0, 0, 0);
                o0 = __builtin_amdgcn_mfma_f32_16x16x16f16(vf[1][dt], pa[1], o0, 0, 0, 0);
                f32x4 o1 = __builtin_amdgcn_mfma_f32_16x16x16f16(vf[2][dt], pa[2], z, 0, 0, 0);
                o1 = __builtin_amdgcn_mfma_f32_16x16x16f16(vf[3][dt], pa[3], o1, 0, 0, 0);
                f32x4 o = o0 + o1;
                f16x4 ov;
#pragma unroll
                for (int ii = 0; ii < 4; ++ii) ov[ii] = (f16)(o[ii] * rq);
                oreg[hh][qt][dt] = ov;
            }
        }
    }
    SCHED_FENCE();
    __syncthreads();   // all xlds reads done -> buffer becomes att

    // ---- write all 3 heads' O^T to att LDS ----
#pragma unroll
    for (int hh = 0; hh < 3; ++hh) {
        const int head = v * 3 + hh;
#pragma unroll
        for (int qt = 0; qt < 4; ++qt)
#pragma unroll
            for (int dt = 0; dt < 2; ++dt)
                *((f16x4*)(xlds + (qt * 16 + l15) * XP + head * 32 + dt * 16 + lg * 4)) = oreg[hh][qt][dt];
    }
    SCHED_FENCE();
    __syncthreads();   // att visible to both waves

    // ---- proj: wave v -> out cols of its 3 heads ----
#pragma unroll
    for (int hh = 0; hh < 3; ++hh) {
        const int head = v * 3 + hh;
        const f16x8* wpb = (const f16x8*)wpp + (size_t)head * 12 * 64 + lane;
#pragma unroll
        for (int nt = 0; nt < 2; ++nt) {
            f16x8 wpf[6];
#pragma unroll
            for (int ks = 0; ks < 6; ++ks)
                wpf[ks] = wpb[(size_t)(nt * 6 + ks) * 64];
            f32x4 bv = *((const f32x4*)(pb + head * 32 + nt * 16 + lg * 4));
#pragma unroll
            for (int qt = 0; qt < 4; ++qt) {
                f32x4 acc = {0.f, 0.f, 0.f, 0.f};
#pragma unroll
                for (int ks = 0; ks < 6; ++ks) {
                    f16x8 af = *((const f16x8*)(xlds + (qt * 16 + l15) * XP + ks * 32 + lg * 8));
                    acc = __builtin_amdgcn_mfma_f32_16x16x32_f16(wpf[ks], af, acc, 0, 0, 0);
                }
                acc += bv;
                const int t = qt * 16 + l15;
                const int gy = wy * 8 + (t >> 3), gx = wx * 8 + (t & 7);
                *((f32x4*)(out + ((size_t)((b * HDIM + gy) * WDIM + gx)) * C_ + head * 32 + nt * 16 + lg * 4)) = acc;
            }
        }
    }
}

extern "C" void kernel_launch(void* const* d_in, const int* in_sizes, int n_in,
                              void* d_out, int out_size, void* d_ws, size_t ws_size,
                              hipStream_t stream) {
    const float* x      = (const float*)d_in[0];
    const float* qkv_w  = (const float*)d_in[1];
    const float* proj_w = (const float*)d_in[2];
    const float* proj_b = (const float*)d_in[3];
    const float* rpb    = (const float*)d_in[4];
    float* out = (float*)d_out;
    char* ws = (char*)d_ws;
    f16* wqp     = (f16*)(ws + OFF_WQ);
    f16* wpp     = (f16*)(ws + OFF_WP);
    float* biasp = (float*)(ws + OFF_BIAS);

    prep_kernel<<<96, 256, 0, stream>>>(qkv_w, proj_w, rpb, wqp, wpp, biasp);
    fused_kernel<<<4096, 128, 0, stream>>>(x, wqp, wpp, proj_b, biasp, out);
}

// Round 19
// 174.638 us; speedup vs baseline: 1.0080x; 1.0080x over previous
//
#include <hip/hip_runtime.h>

typedef _Float16 f16;
typedef _Float16 f16x8 __attribute__((ext_vector_type(8)));
typedef _Float16 f16x4 __attribute__((ext_vector_type(4)));
typedef __fp16 h16x2 __attribute__((ext_vector_type(2)));
typedef float f32x4 __attribute__((ext_vector_type(4)));

constexpr int HDIM = 256, WDIM = 256, C_ = 192, NH_ = 6;
constexpr float SCALE = 0.17677669529663687f;            // 32^-0.5
constexpr float L2E = 1.4426950408889634f;               // log2(e)
constexpr float SCALE2 = SCALE * L2E;                    // folded into q-weights
constexpr int XP = 200;                                  // padded f16 row stride
constexpr int BUF = 64 * XP;                             // f16 elems per window tile

#define SCHED_FENCE() __builtin_amdgcn_sched_barrier(0)

// workspace layout (bytes)
constexpr size_t OFF_WQ   = 0;         // packed qkv weights (q rows pre-scaled): 221184 B
constexpr size_t OFF_WP   = 221184;    // packed proj weights: 73728 B
constexpr size_t OFF_BIAS = 294912;    // packed bias f32 (pre-scaled by log2e), C-layout: 98304 B

__global__ __launch_bounds__(256) void prep_kernel(const float* __restrict__ qkv_w,
                                                   const float* __restrict__ proj_w,
                                                   const float* __restrict__ rpb,
                                                   f16* __restrict__ wqp, f16* __restrict__ wpp,
                                                   float* __restrict__ biasp) {
    int i = blockIdx.x * 256 + threadIdx.x;
    if (i < 13824) {                       // qkv frags: entry = ((w*3+c)*2+dt)*6+ks
        int lane = i & 63, rest = i >> 6;
        int ks = rest % 6; rest /= 6;
        int dt = rest & 1; rest >>= 1;
        int c = rest % 3, w = rest / 3;
        int l15 = lane & 15, lg = lane >> 4;
        int row = c * 192 + w * 32 + dt * 16 + l15;
        int col = ks * 32 + lg * 8;
        float sc = (c == 0) ? SCALE2 : 1.0f;   // fold softmax scale*log2e into q-weights
#pragma unroll
        for (int j = 0; j < 8; ++j) wqp[(size_t)i * 8 + j] = (f16)(qkv_w[row * 192 + col + j] * sc);
    } else if (i < 18432) {                // proj frags: entry = (w*2+nt)*6+ks
        int g = i - 13824;
        int lane = g & 63, rest = g >> 6;
        int ks = rest % 6; rest /= 6;
        int nt = rest & 1, w = rest >> 1;
        int l15 = lane & 15, lg = lane >> 4;
        int row = w * 32 + nt * 16 + l15;
        int col = ks * 32 + lg * 8;
#pragma unroll
        for (int j = 0; j < 8; ++j) wpp[(size_t)g * 8 + j] = (f16)proj_w[row * 192 + col + j];
    } else if (i < 24576) {                // bias frags f32 (*log2e): entry = (h*4+qt)*4+kt
        int g = i - 18432;
        int lane = g & 63;
        int kt = (g >> 6) & 3, qt = (g >> 8) & 3, h = g >> 10;
        int q = qt * 16 + (lane & 15);
#pragma unroll
        for (int j = 0; j < 4; ++j) {
            int k = kt * 16 + (lane >> 4) * 4 + j;
            int dy = (q >> 3) - (k >> 3) + 7;
            int dx = (q & 7) - (k & 7) + 7;
            biasp[(size_t)g * 4 + j] = rpb[(dy * 15 + dx) * NH_ + h] * L2E;
        }
    }
}

// One block = TWO windows, 4 waves: wave v -> window (v>>1), heads 3*(v&1)..+2.
// Same-phase waves of the two windows load identical weight frags -> L1 sharing.
// 2-pass QKV, bias as QK^T C-init, exp2-domain softmax WITH row-max (proven
// R16/R17 numerics). 51.2KB LDS -> 3 blocks/CU = 12 waves/CU.
__global__ __launch_bounds__(256, 3) void fused_kernel(const float* __restrict__ x,
                                                       const f16* __restrict__ wqp,
                                                       const f16* __restrict__ wpp,
                                                       const float* __restrict__ pb,
                                                       const float* __restrict__ biasp,
                                                       float* __restrict__ out) {
    __shared__ f16 xlds[2 * BUF];   // 51200 B; two window tiles, later att tiles
    const int tid = threadIdx.x;
    const int v = tid >> 6;          // wave 0..3
    const int lane = tid & 63;
    const int l15 = lane & 15, lg = lane >> 4;
    const int wb = blockIdx.x * 2;
    const int win = wb + (v >> 1);   // this wave's window
    const int b = win >> 10, wy = (win >> 5) & 31, wx = win & 31;
    f16* mylds = xlds + (v >> 1) * BUF;

    // ---- stage BOTH windows -> LDS, coalesced float4s, 3 fenced groups ----
#pragma unroll
    for (int grp = 0; grp < 3; ++grp) {
#pragma unroll
        for (int it8 = 0; it8 < 8; ++it8) {
            int u = tid + (grp * 8 + it8) * 256;       // 0..6143
            int wh = (u >= 3072) ? 1 : 0;
            int r = u - wh * 3072;
            int row = r / 48, c4 = r - row * 48;
            int ws = wb + wh;
            int bs = ws >> 10, wys = (ws >> 5) & 31, wxs = ws & 31;
            int gy = wys * 8 + (row >> 3), gx = wxs * 8 + (row & 7);
            float4 vv = *((const float4*)(x + ((size_t)((bs * HDIM + gy) * WDIM + gx)) * C_ + c4 * 4));
            h16x2 p0 = __builtin_amdgcn_cvt_pkrtz(vv.x, vv.y);
            h16x2 p1 = __builtin_amdgcn_cvt_pkrtz(vv.z, vv.w);
            f16x4 o4;
            o4[0] = (f16)p0[0]; o4[1] = (f16)p0[1]; o4[2] = (f16)p1[0]; o4[3] = (f16)p1[1];
            *((f16x4*)(xlds + wh * BUF + row * XP + c4 * 4)) = o4;
        }
        SCHED_FENCE();
    }
    __syncthreads();

    f16x4 oreg[3][4][2];   // O^T of this wave's 3 heads, held until att barrier

#pragma unroll
    for (int hh = 0; hh < 3; ++hh) {
        const int head = (v & 1) * 3 + hh;
        const f16x8* wqb   = (const f16x8*)wqp + (size_t)head * 36 * 64 + lane;
        const f32x4* bbase = (const f32x4*)biasp + (size_t)head * 16 * 64 + lane;
        SCHED_FENCE();   // don't hoist this head's loads into previous head

        // ---- pass 1: q,k (shared xt reads) ----
        f16x4 qf[2][4], kf[2][4];
        {
            f32x4 aq[2][4], ak[2][4];
#pragma unroll
            for (int ii = 0; ii < 4; ++ii)
#pragma unroll
                for (int jj = 0; jj < 2; ++jj) {
                    f32x4 z = {0.f, 0.f, 0.f, 0.f};
                    aq[jj][ii] = z; ak[jj][ii] = z;
                }
            __builtin_amdgcn_s_setprio(1);
#pragma unroll
            for (int ks = 0; ks < 6; ++ks) {
                f16x8 Wq0 = wqb[(size_t)(     ks) * 64], Wq1 = wqb[(size_t)( 6 + ks) * 64];
                f16x8 Wk0 = wqb[(size_t)(12 + ks) * 64], Wk1 = wqb[(size_t)(18 + ks) * 64];
#pragma unroll
                for (int tt = 0; tt < 4; ++tt) {
                    f16x8 xt = *((const f16x8*)(mylds + (tt * 16 + l15) * XP + ks * 32 + lg * 8));
                    aq[0][tt] = __builtin_amdgcn_mfma_f32_16x16x32_f16(Wq0, xt, aq[0][tt], 0, 0, 0);
                    aq[1][tt] = __builtin_amdgcn_mfma_f32_16x16x32_f16(Wq1, xt, aq[1][tt], 0, 0, 0);
                    ak[0][tt] = __builtin_amdgcn_mfma_f32_16x16x32_f16(Wk0, xt, ak[0][tt], 0, 0, 0);
                    ak[1][tt] = __builtin_amdgcn_mfma_f32_16x16x32_f16(Wk1, xt, ak[1][tt], 0, 0, 0);
                }
            }
            __builtin_amdgcn_s_setprio(0);
#pragma unroll
            for (int dt = 0; dt < 2; ++dt)
#pragma unroll
                for (int tt = 0; tt < 4; ++tt)
#pragma unroll
                    for (int ii = 0; ii < 4; ++ii) {
                        qf[dt][tt][ii] = (f16)(aq[dt][tt][ii]);   // scale pre-folded in weights
                        kf[dt][tt][ii] = (f16)(ak[dt][tt][ii]);
                    }
        }
        SCHED_FENCE();

        // ---- pass 2: v ----
        f16x4 vf[4][2];
        {
            f32x4 av[4][2];
#pragma unroll
            for (int ii = 0; ii < 4; ++ii)
#pragma unroll
                for (int jj = 0; jj < 2; ++jj) { f32x4 z = {0.f,0.f,0.f,0.f}; av[ii][jj] = z; }
            __builtin_amdgcn_s_setprio(1);
#pragma unroll
            for (int ks = 0; ks < 6; ++ks) {
                f16x8 W0 = wqb[(size_t)(24 + ks) * 64], W1 = wqb[(size_t)(30 + ks) * 64];
#pragma unroll
                for (int tt = 0; tt < 4; ++tt) {
                    f16x8 xt = *((const f16x8*)(mylds + (tt * 16 + l15) * XP + ks * 32 + lg * 8));
                    av[tt][0] = __builtin_amdgcn_mfma_f32_16x16x32_f16(xt, W0, av[tt][0], 0, 0, 0);
                    av[tt][1] = __builtin_amdgcn_mfma_f32_16x16x32_f16(xt, W1, av[tt][1], 0, 0, 0);
                }
            }
            __builtin_amdgcn_s_setprio(0);
#pragma unroll
            for (int tt = 0; tt < 4; ++tt)
#pragma unroll
                for (int dt = 0; dt < 2; ++dt)
#pragma unroll
                    for (int ii = 0; ii < 4; ++ii)
                        vf[tt][dt][ii] = (f16)(av[tt][dt][ii]);
        }
        SCHED_FENCE();

        // ---- attention (exp2 domain, WITH row-max); bias as MFMA C-init ----
#pragma unroll
        for (int qt = 0; qt < 4; ++qt) {
            f32x4 s[4];
#pragma unroll
            for (int kt = 0; kt < 4; ++kt) {
                f32x4 bb = bbase[(size_t)(qt * 4 + kt) * 64];
                s[kt] = __builtin_amdgcn_mfma_f32_16x16x16f16(kf[0][kt], qf[0][qt], bb, 0, 0, 0);
                s[kt] = __builtin_amdgcn_mfma_f32_16x16x16f16(kf[1][kt], qf[1][qt], s[kt], 0, 0, 0);
            }
            float m = s[0][0];
#pragma unroll
            for (int kt = 0; kt < 4; ++kt)
#pragma unroll
                for (int ii = 0; ii < 4; ++ii) m = fmaxf(m, s[kt][ii]);
            m = fmaxf(m, __shfl_xor(m, 16));
            m = fmaxf(m, __shfl_xor(m, 32));
            float sum = 0.f;
            f16x4 pa[4];
#pragma unroll
            for (int kt = 0; kt < 4; ++kt)
#pragma unroll
                for (int ii = 0; ii < 4; ++ii) {
                    float e;
                    asm("v_exp_f32 %0, %1" : "=v"(e) : "v"(s[kt][ii] - m));   // 2^x
                    sum += e;
                    pa[kt][ii] = (f16)e;
                }
            sum += __shfl_xor(sum, 16);
            sum += __shfl_xor(sum, 32);
            const float rq = __builtin_amdgcn_rcpf(sum);

#pragma unroll
            for (int dt = 0; dt < 2; ++dt) {
                f32x4 z = {0.f, 0.f, 0.f, 0.f};
                f32x4 o0 = __builtin_amdgcn_mfma_f32_16x16x16f16(vf[0][dt], pa[0], z, 0, 0, 0);
                o0 = __builtin_amdgcn_mfma_f32_16x16x16f16(vf[1][dt], pa[1], o0, 0, 0, 0);
                f32x4 o1 = __builtin_amdgcn_mfma_f32_16x16x16f16(vf[2][dt], pa[2], z, 0, 0, 0);
                o1 = __builtin_amdgcn_mfma_f32_16x16x16f16(vf[3][dt], pa[3], o1, 0, 0, 0);
                f32x4 o = o0 + o1;
                f16x4 ov;
#pragma unroll
                for (int ii = 0; ii < 4; ++ii) ov[ii] = (f16)(o[ii] * rq);
                oreg[hh][qt][dt] = ov;
            }
        }
    }
    SCHED_FENCE();
    __syncthreads();   // all xlds reads done -> buffers become att

    // ---- write this wave's 3 heads' O^T to its window's att tile ----
#pragma unroll
    for (int hh = 0; hh < 3; ++hh) {
        const int head = (v & 1) * 3 + hh;
#pragma unroll
        for (int qt = 0; qt < 4; ++qt)
#pragma unroll
            for (int dt = 0; dt < 2; ++dt)
                *((f16x4*)(mylds + (qt * 16 + l15) * XP + head * 32 + dt * 16 + lg * 4)) = oreg[hh][qt][dt];
    }
    SCHED_FENCE();
    __syncthreads();   // att visible

    // ---- proj: wave v -> its window's out cols of its 3 heads ----
#pragma unroll
    for (int hh = 0; hh < 3; ++hh) {
        const int head = (v & 1) * 3 + hh;
        const f16x8* wpb = (const f16x8*)wpp + (size_t)head * 12 * 64 + lane;
#pragma unroll
        for (int nt = 0; nt < 2; ++nt) {
            f16x8 wpf[6];
#pragma unroll
            for (int ks = 0; ks < 6; ++ks)
                wpf[ks] = wpb[(size_t)(nt * 6 + ks) * 64];
            f32x4 bv = *((const f32x4*)(pb + head * 32 + nt * 16 + lg * 4));
#pragma unroll
            for (int qt = 0; qt < 4; ++qt) {
                f32x4 acc = {0.f, 0.f, 0.f, 0.f};
#pragma unroll
                for (int ks = 0; ks < 6; ++ks) {
                    f16x8 af = *((const f16x8*)(mylds + (qt * 16 + l15) * XP + ks * 32 + lg * 8));
                    acc = __builtin_amdgcn_mfma_f32_16x16x32_f16(wpf[ks], af, acc, 0, 0, 0);
                }
                acc += bv;
                const int t = qt * 16 + l15;
                const int gy = wy * 8 + (t >> 3), gx = wx * 8 + (t & 7);
                *((f32x4*)(out + ((size_t)((b * HDIM + gy) * WDIM + gx)) * C_ + head * 32 + nt * 16 + lg * 4)) = acc;
            }
        }
    }
}

extern "C" void kernel_launch(void* const* d_in, const int* in_sizes, int n_in,
                              void* d_out, int out_size, void* d_ws, size_t ws_size,
                              hipStream_t stream) {
    const float* x      = (const float*)d_in[0];
    const float* qkv_w  = (const float*)d_in[1];
    const float* proj_w = (const float*)d_in[2];
    const float* proj_b = (const float*)d_in[3];
    const float* rpb    = (const float*)d_in[4];
    float* out = (float*)d_out;
    char* ws = (char*)d_ws;
    f16* wqp     = (f16*)(ws + OFF_WQ);
    f16* wpp     = (f16*)(ws + OFF_WP);
    float* biasp = (float*)(ws + OFF_BIAS);

    prep_kernel<<<96, 256, 0, stream>>>(qkv_w, proj_w, rpb, wqp, wpp, biasp);
    fused_kernel<<<2048, 256, 0, stream>>>(x, wqp, wpp, proj_b, biasp, out);
}

// Round 20
// 167.322 us; speedup vs baseline: 1.0521x; 1.0437x over previous
//
#include <hip/hip_runtime.h>

typedef _Float16 f16;
typedef _Float16 f16x8 __attribute__((ext_vector_type(8)));
typedef _Float16 f16x4 __attribute__((ext_vector_type(4)));
typedef __fp16 h16x2 __attribute__((ext_vector_type(2)));
typedef float f32x4 __attribute__((ext_vector_type(4)));

constexpr int HDIM = 256, WDIM = 256, C_ = 192, NH_ = 6;
constexpr float SCALE = 0.17677669529663687f;            // 32^-0.5
constexpr float L2E = 1.4426950408889634f;               // log2(e)
constexpr float SCALE2 = SCALE * L2E;                    // folded into q-weights
constexpr int BUF = 12288;                               // f16 per window tile (frag-unit layout)

#define SCHED_FENCE() __builtin_amdgcn_sched_barrier(0)
#define KEEP(v) asm volatile("" : "+v"(v))

// workspace layout (bytes)
constexpr size_t OFF_WQ   = 0;         // packed qkv weights (q rows pre-scaled): 221184 B
constexpr size_t OFF_WP   = 221184;    // packed proj weights: 73728 B
constexpr size_t OFF_BIAS = 294912;    // packed bias f32 (pre-scaled by log2e), C-layout: 98304 B

__global__ __launch_bounds__(256) void prep_kernel(const float* __restrict__ qkv_w,
                                                   const float* __restrict__ proj_w,
                                                   const float* __restrict__ rpb,
                                                   f16* __restrict__ wqp, f16* __restrict__ wpp,
                                                   float* __restrict__ biasp) {
    int i = blockIdx.x * 256 + threadIdx.x;
    if (i < 13824) {                       // qkv frags: entry = ((w*3+c)*2+dt)*6+ks
        int lane = i & 63, rest = i >> 6;
        int ks = rest % 6; rest /= 6;
        int dt = rest & 1; rest >>= 1;
        int c = rest % 3, w = rest / 3;
        int l15 = lane & 15, lg = lane >> 4;
        int row = c * 192 + w * 32 + dt * 16 + l15;
        int col = ks * 32 + lg * 8;
        float sc = (c == 0) ? SCALE2 : 1.0f;   // fold softmax scale*log2e into q-weights
#pragma unroll
        for (int j = 0; j < 8; ++j) wqp[(size_t)i * 8 + j] = (f16)(qkv_w[row * 192 + col + j] * sc);
    } else if (i < 18432) {                // proj frags: entry = (w*2+nt)*6+ks
        int g = i - 13824;
        int lane = g & 63, rest = g >> 6;
        int ks = rest % 6; rest /= 6;
        int nt = rest & 1, w = rest >> 1;
        int l15 = lane & 15, lg = lane >> 4;
        int row = w * 32 + nt * 16 + l15;
        int col = ks * 32 + lg * 8;
#pragma unroll
        for (int j = 0; j < 8; ++j) wpp[(size_t)g * 8 + j] = (f16)proj_w[row * 192 + col + j];
    } else if (i < 24576) {                // bias frags f32 (*log2e): entry = (h*4+qt)*4+kt
        int g = i - 18432;
        int lane = g & 63;
        int kt = (g >> 6) & 3, qt = (g >> 8) & 3, h = g >> 10;
        int q = qt * 16 + (lane & 15);
#pragma unroll
        for (int j = 0; j < 4; ++j) {
            int k = kt * 16 + (lane >> 4) * 4 + j;
            int dy = (q >> 3) - (k >> 3) + 7;
            int dx = (q & 7) - (k & 7) + 7;
            biasp[(size_t)g * 4 + j] = rpb[(dy * 15 + dx) * NH_ + h] * L2E;
        }
    }
}

// One block = TWO windows, 4 waves: wave v -> window (v>>1), heads 3*(v&1)..+2.
// LDS in FRAG-UNIT layout: x[row=token][col=chan] stored as unit U(tt,ks,lg) =
// ((tt*6+ks)*4+lg), lane element at U*128 + l15*8 -> every ds_read_b128 is
// lane-contiguous 16B (conflict-free); staging writes are full f16x8 units
// (conflict-free b128 writes). Same layout reused for the att tile.
// 2x12288 f16 = 49152 B -> 3 blocks/CU.
__global__ __launch_bounds__(256, 3) void fused_kernel(const float* __restrict__ x,
                                                       const f16* __restrict__ wqp,
                                                       const f16* __restrict__ wpp,
                                                       const float* __restrict__ pb,
                                                       const float* __restrict__ biasp,
                                                       float* __restrict__ out) {
    __shared__ f16 xlds[2 * BUF];   // 49152 B; two window tiles, later att tiles
    const int tid = threadIdx.x;
    const int v = tid >> 6;          // wave 0..3
    const int lane = tid & 63;
    const int l15 = lane & 15, lg = lane >> 4;
    const int wb = blockIdx.x * 2;
    const int win = wb + (v >> 1);   // this wave's window
    const int b = win >> 10, wy = (win >> 5) & 31, wx = win & 31;
    f16* mylds = xlds + (v >> 1) * BUF;
    const int lbase = lg * 128 + l15 * 8;              // per-lane read offset within a (tt,ks) group
    const int obase = (lg >> 1) * 128 + l15 * 8 + (lg & 1) * 4;  // O^T write offset (dt adds 256)

    // ---- stage BOTH windows -> LDS frag-units: thread u -> (win-half, row, col-group)
    // row = u&63, cg = (u>>6)%24 -> cols cg*8..+7 (two float4s, 32B contiguous).
    // dst unit = (row>>4)*24 + cg  (ks=cg>>2, lg=cg&3), elem (row&15)*8. f16x8 write.
#pragma unroll
    for (int it = 0; it < 12; ++it) {
        int u = tid + it * 256;            // 0..3071
        int wh = (u >= 1536) ? 1 : 0;
        int r = u - wh * 1536;
        int row = r & 63, cg = r >> 6;
        int ws = wb + wh;
        int bs = ws >> 10, wys = (ws >> 5) & 31, wxs = ws & 31;
        int gy = wys * 8 + (row >> 3), gx = wxs * 8 + (row & 7);
        const float4* sp = (const float4*)(x + ((size_t)((bs * HDIM + gy) * WDIM + gx)) * C_ + cg * 8);
        float4 u0 = sp[0], u1 = sp[1];
        h16x2 p0 = __builtin_amdgcn_cvt_pkrtz(u0.x, u0.y);
        h16x2 p1 = __builtin_amdgcn_cvt_pkrtz(u0.z, u0.w);
        h16x2 p2 = __builtin_amdgcn_cvt_pkrtz(u1.x, u1.y);
        h16x2 p3 = __builtin_amdgcn_cvt_pkrtz(u1.z, u1.w);
        f16x8 o8;
        o8[0] = (f16)p0[0]; o8[1] = (f16)p0[1]; o8[2] = (f16)p1[0]; o8[3] = (f16)p1[1];
        o8[4] = (f16)p2[0]; o8[5] = (f16)p2[1]; o8[6] = (f16)p3[0]; o8[7] = (f16)p3[1];
        *((f16x8*)(xlds + wh * BUF + (((row >> 4) * 24 + cg) << 7) + ((row & 15) << 3))) = o8;
        if ((it & 3) == 3) SCHED_FENCE();
    }
    __syncthreads();

    f16x4 oreg[3][4][2];   // O^T of this wave's 3 heads, held until att barrier

#pragma unroll
    for (int hh = 0; hh < 3; ++hh) {
        const int head = (v & 1) * 3 + hh;
        const f16x8* wqb   = (const f16x8*)wqp + (size_t)head * 36 * 64 + lane;
        const f32x4* bbase = (const f32x4*)biasp + (size_t)head * 16 * 64 + lane;
        SCHED_FENCE();   // don't hoist this head's loads into previous head

        // ---- pass 1: q,k (shared xt reads, conflict-free) ----
        f16x4 qf[2][4], kf[2][4];
        {
            f32x4 aq[2][4], ak[2][4];
#pragma unroll
            for (int ii = 0; ii < 4; ++ii)
#pragma unroll
                for (int jj = 0; jj < 2; ++jj) {
                    f32x4 z = {0.f, 0.f, 0.f, 0.f};
                    aq[jj][ii] = z; ak[jj][ii] = z;
                }
            __builtin_amdgcn_s_setprio(1);
#pragma unroll
            for (int ks = 0; ks < 6; ++ks) {
                f16x8 Wq0 = wqb[(size_t)(     ks) * 64], Wq1 = wqb[(size_t)( 6 + ks) * 64];
                f16x8 Wk0 = wqb[(size_t)(12 + ks) * 64], Wk1 = wqb[(size_t)(18 + ks) * 64];
#pragma unroll
                for (int tt = 0; tt < 4; ++tt) {
                    f16x8 xt = *((const f16x8*)(mylds + ((tt * 6 + ks) << 9) + lbase));
                    aq[0][tt] = __builtin_amdgcn_mfma_f32_16x16x32_f16(Wq0, xt, aq[0][tt], 0, 0, 0);
                    aq[1][tt] = __builtin_amdgcn_mfma_f32_16x16x32_f16(Wq1, xt, aq[1][tt], 0, 0, 0);
                    ak[0][tt] = __builtin_amdgcn_mfma_f32_16x16x32_f16(Wk0, xt, ak[0][tt], 0, 0, 0);
                    ak[1][tt] = __builtin_amdgcn_mfma_f32_16x16x32_f16(Wk1, xt, ak[1][tt], 0, 0, 0);
                }
            }
            __builtin_amdgcn_s_setprio(0);
#pragma unroll
            for (int dt = 0; dt < 2; ++dt)
#pragma unroll
                for (int tt = 0; tt < 4; ++tt)
#pragma unroll
                    for (int ii = 0; ii < 4; ++ii) {
                        qf[dt][tt][ii] = (f16)(aq[dt][tt][ii]);   // scale pre-folded in weights
                        kf[dt][tt][ii] = (f16)(ak[dt][tt][ii]);
                    }
        }
        SCHED_FENCE();

        // ---- pass 2: v ----
        f16x4 vf[4][2];
        {
            f32x4 av[4][2];
#pragma unroll
            for (int ii = 0; ii < 4; ++ii)
#pragma unroll
                for (int jj = 0; jj < 2; ++jj) { f32x4 z = {0.f,0.f,0.f,0.f}; av[ii][jj] = z; }
            __builtin_amdgcn_s_setprio(1);
#pragma unroll
            for (int ks = 0; ks < 6; ++ks) {
                f16x8 W0 = wqb[(size_t)(24 + ks) * 64], W1 = wqb[(size_t)(30 + ks) * 64];
#pragma unroll
                for (int tt = 0; tt < 4; ++tt) {
                    f16x8 xt = *((const f16x8*)(mylds + ((tt * 6 + ks) << 9) + lbase));
                    av[tt][0] = __builtin_amdgcn_mfma_f32_16x16x32_f16(xt, W0, av[tt][0], 0, 0, 0);
                    av[tt][1] = __builtin_amdgcn_mfma_f32_16x16x32_f16(xt, W1, av[tt][1], 0, 0, 0);
                }
            }
            __builtin_amdgcn_s_setprio(0);
#pragma unroll
            for (int tt = 0; tt < 4; ++tt)
#pragma unroll
                for (int dt = 0; dt < 2; ++dt)
#pragma unroll
                    for (int ii = 0; ii < 4; ++ii)
                        vf[tt][dt][ii] = (f16)(av[tt][dt][ii]);
        }
        SCHED_FENCE();

        // ---- attention (exp2 domain, WITH row-max); bias as MFMA C-init ----
#pragma unroll
        for (int qt = 0; qt < 4; ++qt) {
            f32x4 s[4];
#pragma unroll
            for (int kt = 0; kt < 4; ++kt) {
                f32x4 bb = bbase[(size_t)(qt * 4 + kt) * 64];
                s[kt] = __builtin_amdgcn_mfma_f32_16x16x16f16(kf[0][kt], qf[0][qt], bb, 0, 0, 0);
                s[kt] = __builtin_amdgcn_mfma_f32_16x16x16f16(kf[1][kt], qf[1][qt], s[kt], 0, 0, 0);
            }
            float m = s[0][0];
#pragma unroll
            for (int kt = 0; kt < 4; ++kt)
#pragma unroll
                for (int ii = 0; ii < 4; ++ii) m = fmaxf(m, s[kt][ii]);
            m = fmaxf(m, __shfl_xor(m, 16));
            m = fmaxf(m, __shfl_xor(m, 32));
            float sum = 0.f;
            f16x4 pa[4];
#pragma unroll
            for (int kt = 0; kt < 4; ++kt)
#pragma unroll
                for (int ii = 0; ii < 4; ++ii) {
                    float e;
                    asm("v_exp_f32 %0, %1" : "=v"(e) : "v"(s[kt][ii] - m));   // 2^x
                    sum += e;
                    pa[kt][ii] = (f16)e;
                }
            sum += __shfl_xor(sum, 16);
            sum += __shfl_xor(sum, 32);
            const float rq = __builtin_amdgcn_rcpf(sum);

#pragma unroll
            for (int dt = 0; dt < 2; ++dt) {
                f32x4 z = {0.f, 0.f, 0.f, 0.f};
                f32x4 o0 = __builtin_amdgcn_mfma_f32_16x16x16f16(vf[0][dt], pa[0], z, 0, 0, 0);
                o0 = __builtin_amdgcn_mfma_f32_16x16x16f16(vf[1][dt], pa[1], o0, 0, 0, 0);
                f32x4 o1 = __builtin_amdgcn_mfma_f32_16x16x16f16(vf[2][dt], pa[2], z, 0, 0, 0);
                o1 = __builtin_amdgcn_mfma_f32_16x16x16f16(vf[3][dt], pa[3], o1, 0, 0, 0);
                f32x4 o = o0 + o1;
                f16x4 ov;
#pragma unroll
                for (int ii = 0; ii < 4; ++ii) ov[ii] = (f16)(o[ii] * rq);
                oreg[hh][qt][dt] = ov;
                KEEP(oreg[hh][qt][dt]);   // pin in VGPRs (do NOT spill to scratch)
            }
        }
    }
    SCHED_FENCE();
    __syncthreads();   // all xlds reads done -> buffers become att

    // ---- write this wave's 3 heads' O^T to its window's att tile (frag layout):
    // att[q=qt*16+l15][c=head*32+dt*16+lg*4+ii] -> unit (qt*6+head)*4 + dt*2+(lg>>1),
    // elem l15*8 + (lg&1)*4. f16x4 write.
#pragma unroll
    for (int hh = 0; hh < 3; ++hh) {
        const int head = (v & 1) * 3 + hh;
#pragma unroll
        for (int qt = 0; qt < 4; ++qt)
#pragma unroll
            for (int dt = 0; dt < 2; ++dt)
                *((f16x4*)(mylds + ((qt * 6 + head) << 9) + dt * 256 + obase)) = oreg[hh][qt][dt];
    }
    SCHED_FENCE();
    __syncthreads();   // att visible

    // ---- proj: wave v -> its window's out cols of its 3 heads.
    // af loaded once per qt (reused across both nt).
#pragma unroll
    for (int hh = 0; hh < 3; ++hh) {
        const int head = (v & 1) * 3 + hh;
        const f16x8* wpb = (const f16x8*)wpp + (size_t)head * 12 * 64 + lane;
        f16x8 wpf[2][6];
#pragma unroll
        for (int nt = 0; nt < 2; ++nt)
#pragma unroll
            for (int ks = 0; ks < 6; ++ks)
                wpf[nt][ks] = wpb[(size_t)(nt * 6 + ks) * 64];
        f32x4 bv[2];
#pragma unroll
        for (int nt = 0; nt < 2; ++nt)
            bv[nt] = *((const f32x4*)(pb + head * 32 + nt * 16 + lg * 4));
#pragma unroll
        for (int qt = 0; qt < 4; ++qt) {
            f16x8 af[6];
#pragma unroll
            for (int ks = 0; ks < 6; ++ks)
                af[ks] = *((const f16x8*)(mylds + ((qt * 6 + ks) << 9) + lbase));
            const int t = qt * 16 + l15;
            const int gy = wy * 8 + (t >> 3), gx = wx * 8 + (t & 7);
            float* orow = out + ((size_t)((b * HDIM + gy) * WDIM + gx)) * C_ + head * 32;
#pragma unroll
            for (int nt = 0; nt < 2; ++nt) {
                f32x4 acc = {0.f, 0.f, 0.f, 0.f};
#pragma unroll
                for (int ks = 0; ks < 6; ++ks)
                    acc = __builtin_amdgcn_mfma_f32_16x16x32_f16(wpf[nt][ks], af[ks], acc, 0, 0, 0);
                acc += bv[nt];
                *((f32x4*)(orow + nt * 16 + lg * 4)) = acc;
            }
        }
    }
}

extern "C" void kernel_launch(void* const* d_in, const int* in_sizes, int n_in,
                              void* d_out, int out_size, void* d_ws, size_t ws_size,
                              hipStream_t stream) {
    const float* x      = (const float*)d_in[0];
    const float* qkv_w  = (const float*)d_in[1];
    const float* proj_w = (const float*)d_in[2];
    const float* proj_b = (const float*)d_in[3];
    const float* rpb    = (const float*)d_in[4];
    float* out = (float*)d_out;
    char* ws = (char*)d_ws;
    f16* wqp     = (f16*)(ws + OFF_WQ);
    f16* wpp     = (f16*)(ws + OFF_WP);
    float* biasp = (float*)(ws + OFF_BIAS);

    prep_kernel<<<96, 256, 0, stream>>>(qkv_w, proj_w, rpb, wqp, wpp, biasp);
    fused_kernel<<<2048, 256, 0, stream>>>(x, wqp, wpp, proj_b, biasp, out);
}